// Round 4
// baseline (691.823 us; speedup 1.0000x reference)
//
#include <hip/hip_runtime.h>
#include <hip/hip_bf16.h>
#include <math.h>

// Problem constants
#define NTOK 4096
#define DM   1024
#define NE   16
#define HID  2048
#define NPAIR (NTOK*2)

// GEMM tiling: block 128x128, BK=32, 256 threads = 4 waves,
// wave tile 64x64 (4x4 fragments of 16x16), LDS rows padded to 40 shorts
// (80B row stride -> (5r+fg)%8 covers all bank-quads -> conflict-free b128).
#define BM 128
#define BN 128
#define BK 32
#define LDT 40
#define MSLOTS (NPAIR/BM + NE)   // 64 + 16 = 80

typedef __attribute__((ext_vector_type(4))) float f32x4;
typedef __attribute__((ext_vector_type(8))) short bf16x8;

__device__ __forceinline__ float gelu_exact(float v) {
    return 0.5f * v * (1.0f + erff(v * 0.70710678118654752440f));
}
__device__ __forceinline__ short f2bf(float f) {
    __hip_bfloat16 b = __float2bfloat16(f);
    return __builtin_bit_cast(short, b);
}

// ---------------------------------------------------------------------------
// Routing compaction
// ---------------------------------------------------------------------------
__global__ void k_init(float* __restrict__ out, int* __restrict__ cnt, int* __restrict__ cnt2) {
    int i = blockIdx.x * blockDim.x + threadIdx.x;
    if (i < NTOK * DM / 4) ((float4*)out)[i] = make_float4(0.f, 0.f, 0.f, 0.f);
    if (i < NE) { cnt[i] = 0; cnt2[i] = 0; }
}

__global__ void k_count(const float* __restrict__ rt, int* __restrict__ cnt) {
    int i = blockIdx.x * blockDim.x + threadIdx.x;
    if (i >= NTOK * NE) return;
    if (rt[i] > 0.0f) atomicAdd(&cnt[i & (NE - 1)], 1);
}

__global__ void k_scan(const int* __restrict__ cnt, int* __restrict__ offs, int* __restrict__ ts) {
    int o = 0, t = 0;
    for (int e = 0; e < NE; ++e) {
        offs[e] = o; ts[e] = t;
        o += cnt[e];
        t += (cnt[e] + BM - 1) / BM;
    }
    ts[NE] = t;
}

__global__ void k_fill(const float* __restrict__ rt, const int* __restrict__ offs,
                       int* __restrict__ cnt2, int* __restrict__ ptok, float* __restrict__ pscore) {
    int i = blockIdx.x * blockDim.x + threadIdx.x;
    if (i >= NTOK * NE) return;
    float s = rt[i];
    if (s > 0.0f) {
        int e = i & (NE - 1);
        int n = i >> 4;
        int slot = atomicAdd(&cnt2[e], 1);
        int pos = offs[e] + slot;
        ptok[pos] = n;
        pscore[pos] = s;
    }
}

// ---------------------------------------------------------------------------
// GEMM1 (MFMA): h[pos,:] = gelu(x[tok[pos],:] @ W0[e] + b0[e]), bf16 out
// ---------------------------------------------------------------------------
__global__ __launch_bounds__(256, 3) void k_gemm1(
    const float* __restrict__ x, const float* __restrict__ W0, const float* __restrict__ b0,
    const int* __restrict__ cnt, const int* __restrict__ offs, const int* __restrict__ ts,
    const int* __restrict__ ptok, short* __restrict__ h)
{
    __shared__ short As[BM * LDT];
    __shared__ short Bs[BN * LDT];
    __shared__ int toks_s[BM];

    int mt = blockIdx.x;
    if (mt >= ts[NE]) return;
    int e = 0;
    while (mt >= ts[e + 1]) ++e;
    int lm = mt - ts[e];
    int row0 = offs[e] + lm * BM;
    int rowsValid = min(BM, cnt[e] - lm * BM);
    int n0 = blockIdx.y * BN;
    int tid = threadIdx.x;

    if (tid < BM) toks_s[tid] = ptok[row0 + min(tid, rowsValid - 1)];
    __syncthreads();

    const float* W0e = W0 + (size_t)e * DM * HID;
    int lane = tid & 63, wid = tid >> 6;
    int wm = wid >> 1, wn = wid & 1;
    int fr = lane & 15, fg = lane >> 4;

    // A staging: 2 threads per row, 64B (16 floats) each
    int arow = tid >> 1, ahalf = tid & 1;
    const float* aptr = x + (size_t)toks_s[arow] * DM + ahalf * 16;
    // B staging: thread -> 2 adjacent n-cols x 8 k-rows (float2, coalesced)
    int n2 = (tid & 63) * 2, kq = tid >> 6;
    const float* bptr = W0e + (size_t)(kq * 8) * HID + n0 + n2;

    f32x4 acc[4][4];
#pragma unroll
    for (int i = 0; i < 4; ++i)
#pragma unroll
        for (int j = 0; j < 4; ++j) acc[i][j] = (f32x4)0.0f;

    float4 ar0[4], ar1[4];
    float2 br0[8], br1[8];

    auto LOAD = [&](float4 (&ar)[4], float2 (&br)[8], int kt) {
#pragma unroll
        for (int j = 0; j < 4; ++j) ar[j] = *(const float4*)(aptr + kt + j * 4);
#pragma unroll
        for (int s = 0; s < 8; ++s) br[s] = *(const float2*)(bptr + (size_t)(kt + s) * HID);
    };

    auto STEP = [&](float4 (&ar)[4], float2 (&br)[8],
                    float4 (&arN)[4], float2 (&brN)[8], int kt) {
        float av[16] = {ar[0].x, ar[0].y, ar[0].z, ar[0].w,
                        ar[1].x, ar[1].y, ar[1].z, ar[1].w,
                        ar[2].x, ar[2].y, ar[2].z, ar[2].w,
                        ar[3].x, ar[3].y, ar[3].z, ar[3].w};
        bf16x8 pa0, pa1, pb0, pb1;
#pragma unroll
        for (int u = 0; u < 8; ++u) { pa0[u] = f2bf(av[u]); pa1[u] = f2bf(av[u + 8]); }
#pragma unroll
        for (int s = 0; s < 8; ++s) { pb0[s] = f2bf(br[s].x); pb1[s] = f2bf(br[s].y); }
        *(bf16x8*)&As[arow * LDT + ahalf * 16]     = pa0;
        *(bf16x8*)&As[arow * LDT + ahalf * 16 + 8] = pa1;
        *(bf16x8*)&Bs[n2 * LDT + kq * 8]       = pb0;
        *(bf16x8*)&Bs[(n2 + 1) * LDT + kq * 8] = pb1;
        __syncthreads();
        if (kt + BK < DM) LOAD(arN, brN, kt + BK);
        bf16x8 bfr[4];
#pragma unroll
        for (int j = 0; j < 4; ++j)
            bfr[j] = *(bf16x8*)&Bs[(wn * 64 + j * 16 + fr) * LDT + fg * 8];
#pragma unroll
        for (int i = 0; i < 4; ++i) {
            bf16x8 af = *(bf16x8*)&As[(wm * 64 + i * 16 + fr) * LDT + fg * 8];
#pragma unroll
            for (int j = 0; j < 4; ++j)
                acc[i][j] = __builtin_amdgcn_mfma_f32_16x16x32_bf16(af, bfr[j], acc[i][j], 0, 0, 0);
        }
        __syncthreads();
    };

    LOAD(ar0, br0, 0);
    for (int kt = 0; kt < DM; kt += 2 * BK) {
        STEP(ar0, br0, ar1, br1, kt);
        STEP(ar1, br1, ar0, br0, kt + BK);
    }

    const float* b0e = b0 + (size_t)e * HID + n0 + wn * 64;
    float bias[4];
#pragma unroll
    for (int j = 0; j < 4; ++j) bias[j] = b0e[j * 16 + fr];
#pragma unroll
    for (int i = 0; i < 4; ++i)
#pragma unroll
        for (int r = 0; r < 4; ++r) {
            int m = wm * 64 + i * 16 + fg * 4 + r;
            if (m < rowsValid) {
                short* hrow = h + (size_t)(row0 + m) * HID + n0 + wn * 64;
#pragma unroll
                for (int j = 0; j < 4; ++j)
                    hrow[j * 16 + fr] = f2bf(gelu_exact(acc[i][j][r] + bias[j]));
            }
        }
}

// ---------------------------------------------------------------------------
// GEMM2 (MFMA): out[tok[pos],:] += score * (h[pos,:] @ W1[e] + b1[e])
// ---------------------------------------------------------------------------
__global__ __launch_bounds__(256, 3) void k_gemm2(
    const short* __restrict__ h, const float* __restrict__ W1, const float* __restrict__ b1,
    const int* __restrict__ cnt, const int* __restrict__ offs, const int* __restrict__ ts,
    const int* __restrict__ ptok, const float* __restrict__ pscore,
    float* __restrict__ out)
{
    __shared__ short As[BM * LDT];
    __shared__ short Bs[BN * LDT];
    __shared__ int toks_s[BM];
    __shared__ float scs_s[BM];

    int mt = blockIdx.x;
    if (mt >= ts[NE]) return;
    int e = 0;
    while (mt >= ts[e + 1]) ++e;
    int lm = mt - ts[e];
    int row0 = offs[e] + lm * BM;
    int rowsValid = min(BM, cnt[e] - lm * BM);
    int n0 = blockIdx.y * BN;
    int tid = threadIdx.x;

    if (tid < BM) {
        int r = min(tid, rowsValid - 1);
        toks_s[tid] = ptok[row0 + r];
        scs_s[tid]  = pscore[row0 + r];
    }
    __syncthreads();

    const float* W1e = W1 + (size_t)e * HID * DM;
    int lane = tid & 63, wid = tid >> 6;
    int wm = wid >> 1, wn = wid & 1;
    int fr = lane & 15, fg = lane >> 4;

    int arow = tid >> 1, ahalf = tid & 1;
    const short* aptr = h + (size_t)(row0 + min(arow, rowsValid - 1)) * HID + ahalf * 16;
    int n2 = (tid & 63) * 2, kq = tid >> 6;
    const float* bptr = W1e + (size_t)(kq * 8) * DM + n0 + n2;

    f32x4 acc[4][4];
#pragma unroll
    for (int i = 0; i < 4; ++i)
#pragma unroll
        for (int j = 0; j < 4; ++j) acc[i][j] = (f32x4)0.0f;

    bf16x8 ha0[2], ha1[2];
    float2 br0[8], br1[8];

    auto LOAD = [&](bf16x8 (&ha)[2], float2 (&br)[8], int kt) {
        ha[0] = *(const bf16x8*)(aptr + kt);
        ha[1] = *(const bf16x8*)(aptr + kt + 8);
#pragma unroll
        for (int s = 0; s < 8; ++s) br[s] = *(const float2*)(bptr + (size_t)(kt + s) * DM);
    };

    auto STEP = [&](bf16x8 (&ha)[2], float2 (&br)[8],
                    bf16x8 (&haN)[2], float2 (&brN)[8], int kt) {
        bf16x8 pb0, pb1;
#pragma unroll
        for (int s = 0; s < 8; ++s) { pb0[s] = f2bf(br[s].x); pb1[s] = f2bf(br[s].y); }
        *(bf16x8*)&As[arow * LDT + ahalf * 16]     = ha[0];
        *(bf16x8*)&As[arow * LDT + ahalf * 16 + 8] = ha[1];
        *(bf16x8*)&Bs[n2 * LDT + kq * 8]       = pb0;
        *(bf16x8*)&Bs[(n2 + 1) * LDT + kq * 8] = pb1;
        __syncthreads();
        if (kt + BK < HID) LOAD(haN, brN, kt + BK);
        bf16x8 bfr[4];
#pragma unroll
        for (int j = 0; j < 4; ++j)
            bfr[j] = *(bf16x8*)&Bs[(wn * 64 + j * 16 + fr) * LDT + fg * 8];
#pragma unroll
        for (int i = 0; i < 4; ++i) {
            bf16x8 af = *(bf16x8*)&As[(wm * 64 + i * 16 + fr) * LDT + fg * 8];
#pragma unroll
            for (int j = 0; j < 4; ++j)
                acc[i][j] = __builtin_amdgcn_mfma_f32_16x16x32_bf16(af, bfr[j], acc[i][j], 0, 0, 0);
        }
        __syncthreads();
    };

    LOAD(ha0, br0, 0);
    for (int kt = 0; kt < HID; kt += 2 * BK) {
        STEP(ha0, br0, ha1, br1, kt);
        STEP(ha1, br1, ha0, br0, kt + BK);
    }

    const float* b1e = b1 + (size_t)e * DM + n0 + wn * 64;
    float bias[4];
#pragma unroll
    for (int j = 0; j < 4; ++j) bias[j] = b1e[j * 16 + fr];
#pragma unroll
    for (int i = 0; i < 4; ++i)
#pragma unroll
        for (int r = 0; r < 4; ++r) {
            int m = wm * 64 + i * 16 + fg * 4 + r;
            if (m < rowsValid) {
                float sc = scs_s[m];
                float* orow = out + (size_t)toks_s[m] * DM + n0 + wn * 64;
#pragma unroll
                for (int j = 0; j < 4; ++j)
                    atomicAdd(&orow[j * 16 + fr], sc * (acc[i][j][r] + bias[j]));
            }
        }
}

// ---------------------------------------------------------------------------
// Launch
// ---------------------------------------------------------------------------
extern "C" void kernel_launch(void* const* d_in, const int* in_sizes, int n_in,
                              void* d_out, int out_size, void* d_ws, size_t ws_size,
                              hipStream_t stream) {
    const float* x  = (const float*)d_in[0];
    const float* rt = (const float*)d_in[1];
    const float* W0 = (const float*)d_in[2];
    const float* b0 = (const float*)d_in[3];
    const float* W1 = (const float*)d_in[4];
    const float* b1 = (const float*)d_in[5];
    float* out = (float*)d_out;

    char* ws = (char*)d_ws;
    int* cnt  = (int*)ws;
    int* cnt2 = cnt + 16;
    int* offs = cnt + 32;
    int* ts   = cnt + 48;
    int*   ptok   = (int*)(ws + 512);
    float* pscore = (float*)(ws + 512 + NPAIR * 4);
    short* hbuf   = (short*)(ws + (1u << 20));   // bf16 h, NPAIR x HID = 33.5 MB

    k_init<<<(NTOK * DM / 4 + 255) / 256, 256, 0, stream>>>(out, cnt, cnt2);
    k_count<<<(NTOK * NE) / 256, 256, 0, stream>>>(rt, cnt);
    k_scan<<<1, 1, 0, stream>>>(cnt, offs, ts);
    k_fill<<<(NTOK * NE) / 256, 256, 0, stream>>>(rt, offs, cnt2, ptok, pscore);

    k_gemm1<<<dim3(MSLOTS, HID / BN), 256, 0, stream>>>(x, W0, b0, cnt, offs, ts, ptok, hbuf);
    k_gemm2<<<dim3(MSLOTS, DM / BN), 256, 0, stream>>>(hbuf, W1, b1, cnt, offs, ts, ptok, pscore, out);
}